// Round 1
// baseline (428.176 us; speedup 1.0000x reference)
//
#include <hip/hip_runtime.h>
#include <hip/hip_bf16.h>

typedef unsigned short u16;
typedef unsigned int u32;
typedef short bf16x8 __attribute__((ext_vector_type(8)));
typedef float f32x4 __attribute__((ext_vector_type(4)));

__device__ inline float bf2f(u16 u) { return __uint_as_float(((u32)u) << 16); }
__device__ inline u16 f2bf(float f) {
    u32 x = __float_as_uint(f);
    return (u16)((x + 0x7FFFu + ((x >> 16) & 1u)) >> 16);  // RNE
}

// ---------------- Kernel 1: Wh_t[b][f][j] = (x @ W)^T, bf16 ----------------
// Formulated as W^T(f,k) @ x^T(k,j): M=f=128, N=j=128/block, K=128.
__global__ __launch_bounds__(256) void k_gemm1(const float* __restrict__ x,
                                               const float* __restrict__ W,
                                               u16* __restrict__ Wht) {
    __shared__ __align__(16) u16 Wt[128][136];  // [f][k], +8 pad
    const int t = threadIdx.x;
    {   // stage W^T into LDS (bf16)
        int k = t >> 1;
        int f0 = (t & 1) * 64;
        const float4* wp = reinterpret_cast<const float4*>(W + k * 128 + f0);
#pragma unroll
        for (int q = 0; q < 16; ++q) {
            float4 v = wp[q];
            int f = f0 + q * 4;
            Wt[f + 0][k] = f2bf(v.x);
            Wt[f + 1][k] = f2bf(v.y);
            Wt[f + 2][k] = f2bf(v.z);
            Wt[f + 3][k] = f2bf(v.w);
        }
    }
    __syncthreads();

    const int w = t >> 6, l = t & 63;
    const int lr = l & 15, lg = l >> 4;
    const int fh = (w & 1) * 64;
    const int jh = (w >> 1) * 64;
    const int j0 = blockIdx.x * 128;  // flat row in x (B*N)

    f32x4 acc[4][4];
#pragma unroll
    for (int m = 0; m < 4; ++m)
#pragma unroll
        for (int n = 0; n < 4; ++n) acc[m][n] = (f32x4){0.f, 0.f, 0.f, 0.f};

#pragma unroll
    for (int ks = 0; ks < 4; ++ks) {
        bf16x8 a[4], bb[4];
#pragma unroll
        for (int m = 0; m < 4; ++m)
            a[m] = *reinterpret_cast<const bf16x8*>(&Wt[fh + m * 16 + lr][ks * 32 + lg * 8]);
#pragma unroll
        for (int n = 0; n < 4; ++n) {
            int j = j0 + jh + n * 16 + lr;
            const float* xp = x + (size_t)j * 128 + ks * 32 + lg * 8;
            float4 v0 = *reinterpret_cast<const float4*>(xp);
            float4 v1 = *reinterpret_cast<const float4*>(xp + 4);
            bf16x8 bv;
            bv[0] = (short)f2bf(v0.x); bv[1] = (short)f2bf(v0.y);
            bv[2] = (short)f2bf(v0.z); bv[3] = (short)f2bf(v0.w);
            bv[4] = (short)f2bf(v1.x); bv[5] = (short)f2bf(v1.y);
            bv[6] = (short)f2bf(v1.z); bv[7] = (short)f2bf(v1.w);
            bb[n] = bv;
        }
#pragma unroll
        for (int m = 0; m < 4; ++m)
#pragma unroll
            for (int n = 0; n < 4; ++n)
                acc[m][n] = __builtin_amdgcn_mfma_f32_16x16x32_bf16(a[m], bb[n], acc[m][n], 0, 0, 0);
    }

    // C layout: col(=j) = lane&15, row(=f) = (lane>>4)*4 + reg
    const int bb_ = blockIdx.x >> 5;          // batch
    const int jj = (blockIdx.x & 31) * 128;   // j within batch
    u16* base = Wht + ((size_t)bb_ << 19);    // 128*4096 per batch
#pragma unroll
    for (int m = 0; m < 4; ++m) {
        int f = fh + m * 16 + lg * 4;
#pragma unroll
        for (int n = 0; n < 4; ++n) {
            int j = jj + jh + n * 16 + lr;
#pragma unroll
            for (int r = 0; r < 4; ++r)
                base[(size_t)(f + r) * 4096 + j] = f2bf(acc[m][n][r]);
        }
    }
}

// ---------------- Kernel 2: S_all[b*128+f] = sum_j Wh_t[b][f][j] ----------------
__global__ __launch_bounds__(64) void k_colsum(const u16* __restrict__ Wht,
                                               float* __restrict__ S) {
    const int row = blockIdx.x;  // b*128 + f
    const uint4* p = reinterpret_cast<const uint4*>(Wht + (size_t)row * 4096);
    const int l = threadIdx.x;
    float s = 0.f;
#pragma unroll
    for (int q = 0; q < 8; ++q) {
        uint4 v = p[l * 8 + q];
        u32 arr[4] = {v.x, v.y, v.z, v.w};
#pragma unroll
        for (int e = 0; e < 4; ++e)
            s += bf2f((u16)(arr[e] & 0xFFFFu)) + bf2f((u16)(arr[e] >> 16));
    }
#pragma unroll
    for (int off = 32; off; off >>= 1) s += __shfl_xor(s, off);
    if (l == 0) S[row] = s;
}

// ---------------- Kernel 3: out[b][i][f] = (1/cnt_i) * sum_{j: adj>0} Wh[b][j][f] ----------------
// MFMA: M=i (BM=64), N=f (128), K=j (4096, BK=64). A = adj tile (bf16 0/1), B = Wh_t tile.
__global__ __launch_bounds__(256) void k_gemm2(const int* __restrict__ adj,
                                               const u16* __restrict__ Wht,
                                               const float* __restrict__ S,
                                               float* __restrict__ out) {
    __shared__ __align__(16) u16 As[2][64][72];
    __shared__ __align__(16) u16 Bs[2][128][72];
    __shared__ int cnt_lds[64];
    __shared__ float inv_lds[64];

    const int t = threadIdx.x;
    const int b = blockIdx.x >> 6;
    const int i0 = (blockIdx.x & 63) * 64;
    const int* adjb = adj + ((size_t)b << 24) + (size_t)i0 * 4096;
    const u16* whb = Wht + ((size_t)b << 19);

    // staging assignments
    const int ai = t >> 2;            // A row 0..63
    const int ak = (t & 3) * 16;      // A k-chunk (16 ints)
    const int bf = t >> 1;            // B row (f) 0..127
    const int bk = (t & 1) * 32;      // B k-chunk (32 bf16)

    int4 av[4];
    uint4 bv[4];
    int cnt = 0;

    auto issue = [&](int k0) {
        const int4* ap = reinterpret_cast<const int4*>(adjb + (size_t)ai * 4096 + k0 + ak);
        av[0] = ap[0]; av[1] = ap[1]; av[2] = ap[2]; av[3] = ap[3];
        const uint4* bp = reinterpret_cast<const uint4*>(whb + (size_t)bf * 4096 + k0 + bk);
        bv[0] = bp[0]; bv[1] = bp[1]; bv[2] = bp[2]; bv[3] = bp[3];
    };
    auto convert_write = [&](int buf) {
        u32 u[8];
#pragma unroll
        for (int q = 0; q < 4; ++q) {
            int4 v = av[q];
            u32 e0 = (v.x > 0) ? 0x3F80u : 0u;
            u32 e1 = (v.y > 0) ? 0x3F80u : 0u;
            u32 e2 = (v.z > 0) ? 0x3F80u : 0u;
            u32 e3 = (v.w > 0) ? 0x3F80u : 0u;
            cnt += (v.x > 0) + (v.y > 0) + (v.z > 0) + (v.w > 0);
            u[q * 2 + 0] = e0 | (e1 << 16);
            u[q * 2 + 1] = e2 | (e3 << 16);
        }
        uint4* aw = reinterpret_cast<uint4*>(&As[buf][ai][ak]);
        aw[0] = make_uint4(u[0], u[1], u[2], u[3]);
        aw[1] = make_uint4(u[4], u[5], u[6], u[7]);
        uint4* bw = reinterpret_cast<uint4*>(&Bs[buf][bf][bk]);
        bw[0] = bv[0]; bw[1] = bv[1]; bw[2] = bv[2]; bw[3] = bv[3];
    };

    const int w = t >> 6, l = t & 63;
    const int lr = l & 15, lg = l >> 4;
    const int ir0 = (w >> 1) * 2;  // 2 i-frags per wave
    const int fr0 = (w & 1) * 4;   // 4 f-frags per wave

    f32x4 acc[2][4];
#pragma unroll
    for (int m = 0; m < 2; ++m)
#pragma unroll
        for (int n = 0; n < 4; ++n) acc[m][n] = (f32x4){0.f, 0.f, 0.f, 0.f};

    issue(0);
    convert_write(0);
    __syncthreads();

    for (int kt = 0; kt < 64; ++kt) {
        const int cur = kt & 1;
        const bool pre = (kt + 1 < 64);
        if (pre) issue((kt + 1) * 64);  // prefetch next tile into regs (overlaps MFMA)

#pragma unroll
        for (int ks = 0; ks < 2; ++ks) {
            bf16x8 a[2], bb[4];
#pragma unroll
            for (int m = 0; m < 2; ++m)
                a[m] = *reinterpret_cast<const bf16x8*>(&As[cur][(ir0 + m) * 16 + lr][ks * 32 + lg * 8]);
#pragma unroll
            for (int n = 0; n < 4; ++n)
                bb[n] = *reinterpret_cast<const bf16x8*>(&Bs[cur][(fr0 + n) * 16 + lr][ks * 32 + lg * 8]);
#pragma unroll
            for (int m = 0; m < 2; ++m)
#pragma unroll
                for (int n = 0; n < 4; ++n)
                    acc[m][n] = __builtin_amdgcn_mfma_f32_16x16x32_bf16(a[m], bb[n], acc[m][n], 0, 0, 0);
        }

        if (pre) convert_write(cur ^ 1);
        __syncthreads();
    }

    // reduce per-row counts: threads 4i..4i+3 hold partials for row i
    int c2 = cnt + __shfl_xor(cnt, 1);
    int c4 = c2 + __shfl_xor(c2, 2);
    if ((t & 3) == 0) cnt_lds[ai] = c4;
    __syncthreads();
    if (t < 64) {
        int c = cnt_lds[t];
        inv_lds[t] = (c > 0) ? (1.0f / (float)c) : 0.0f;
    }
    __syncthreads();

    float* ob = out + (((size_t)b * 4096) + i0) * 128;
#pragma unroll
    for (int m = 0; m < 2; ++m) {
#pragma unroll
        for (int n = 0; n < 4; ++n) {
            int f = (fr0 + n) * 16 + lr;
#pragma unroll
            for (int r = 0; r < 4; ++r) {
                int il = (ir0 + m) * 16 + lg * 4 + r;
                int c = cnt_lds[il];
                float v;
                if (c > 0) v = acc[m][n][r] * inv_lds[il];
                else       v = S[b * 128 + f] * (1.0f / 4096.0f);  // empty row: uniform softmax
                ob[(size_t)il * 128 + f] = v;
            }
        }
    }
}

extern "C" void kernel_launch(void* const* d_in, const int* in_sizes, int n_in,
                              void* d_out, int out_size, void* d_ws, size_t ws_size,
                              hipStream_t stream) {
    const float* x = (const float*)d_in[0];
    const int* adj = (const int*)d_in[1];
    const float* W = (const float*)d_in[2];
    // d_in[3] (a) is mathematically dead: softmax of a j-constant over the adj
    // support is uniform, so attention = adj / rowsum(adj).
    float* out = (float*)d_out;

    u16* Wht = (u16*)d_ws;                                   // 4*128*4096 bf16 = 4 MB
    float* S = (float*)((char*)d_ws + (size_t)4 * 128 * 4096 * 2);  // 512 f32

    k_gemm1<<<128, 256, 0, stream>>>(x, W, Wht);
    k_colsum<<<512, 64, 0, stream>>>(Wht, S);
    k_gemm2<<<256, 256, 0, stream>>>(adj, Wht, S, out);
}